// Round 13
// baseline (212.281 us; speedup 1.0000x reference)
//
#include <hip/hip_runtime.h>
#include <math.h>

#define HIDDEN 1024
#define NH 16
#define NKV 4
#define HD 64
#define BS_ 2
#define SEQ_ 2048
#define WIN 1534   // allowed iff k - q <= 1534
#define LOG2E 1.4426950408889634f

typedef unsigned short u16;
typedef short short8 __attribute__((ext_vector_type(8)));
typedef float f32x4 __attribute__((ext_vector_type(4)));
typedef float f32x16 __attribute__((ext_vector_type(16)));
typedef u16 u16x4 __attribute__((ext_vector_type(4)));

// s_waitcnt: vmcnt low[3:0], expcnt[6:4]=7 (no wait), lgkmcnt[12:8]=31 (no wait)
#define WAITVM(n) __builtin_amdgcn_s_waitcnt(0x1f70 | (n))

__device__ __forceinline__ u16 f2bf(float f) {
    unsigned u = __float_as_uint(f);
    u += 0x7fff + ((u >> 16) & 1);      // RNE
    return (u16)(u >> 16);
}

// pack two f32 -> two bf16 (truncation) in ONE v_perm_b32
__device__ __forceinline__ unsigned pk_trunc(float lo, float hi) {
    return __builtin_amdgcn_perm(__float_as_uint(hi), __float_as_uint(lo), 0x07060302u);
}

__device__ __forceinline__ void async_ld16(const u16* g, u16* l) {
    __builtin_amdgcn_global_load_lds(
        (const __attribute__((address_space(1))) unsigned int*)g,
        (__attribute__((address_space(3))) unsigned int*)l, 16, 0, 0);
}

// -------- cast fp32 -> bf16 (X + 4 weights), pre-scale amask, build RoPE LUT --------
#define C_X  1048576
#define C_WQ 1310720
#define C_WK 1376256
#define C_WV 1441792
#define C_WO 1703936
#define C_AM 1704960
__global__ __launch_bounds__(256) void cast6(
    const float* __restrict__ x, const float* __restrict__ wq,
    const float* __restrict__ wk, const float* __restrict__ wv,
    const float* __restrict__ wo, const float* __restrict__ amask,
    u16* __restrict__ xb, u16* __restrict__ wqb, u16* __restrict__ wkb,
    u16* __restrict__ wvb, u16* __restrict__ wob, float* __restrict__ ams,
    float2* __restrict__ rtab)
{
    if (blockIdx.x >= 6660) {
        int i = (blockIdx.x - 6660) * 256 + threadIdx.x;   // (s, j) over 2048 x 32
        int s = i >> 5, j = i & 31;
        float inv = powf(10000.0f, -(float)j * (1.0f / 32.0f));
        float sn, cs;
        sincosf((float)s * inv, &sn, &cs);
        rtab[i] = make_float2(cs, sn);
        return;
    }
    int c = blockIdx.x * 256 + threadIdx.x;   // 4-elem chunk id
    const float* src; u16* dst; int base;
    if (c < C_X)       { src = x;  dst = xb;  base = 0; }
    else if (c < C_WQ) { src = wq; dst = wqb; base = C_X; }
    else if (c < C_WK) { src = wk; dst = wkb; base = C_WQ; }
    else if (c < C_WV) { src = wv; dst = wvb; base = C_WK; }
    else if (c < C_WO) { src = wo; dst = wob; base = C_WV; }
    else {
        int i = (c - C_WO) * 4;
        const float sc = -10000.0f * LOG2E;
        float4 v = *(const float4*)(amask + i);
        *(float4*)(ams + i) = make_float4(v.x * sc, v.y * sc, v.z * sc, v.w * sc);
        return;
    }
    int i = (c - base) * 4;
    float4 v = *(const float4*)(src + i);
    u16x4 o = {f2bf(v.x), f2bf(v.y), f2bf(v.z), f2bf(v.w)};
    *(u16x4*)(dst + i) = o;
}

// ---------------- fused QKV MFMA GEMM, 128x64 tile, XCD-affine (R11) ----------------
__global__ __launch_bounds__(256) void gemm_qkv(
    const u16* __restrict__ Xb, const u16* __restrict__ Wqb,
    const u16* __restrict__ Wkb, const u16* __restrict__ Wvb,
    const float* __restrict__ bq, const float* __restrict__ bk,
    const float* __restrict__ bv, const float2* __restrict__ rtab,
    u16* __restrict__ Qp, u16* __restrict__ Kp, u16* __restrict__ Vtp)
{
    __shared__ u16 sA[128 * 32];   // 8 KB
    __shared__ u16 sB[64 * 32];    // 4 KB
    int tid = threadIdx.x, lane = tid & 63, wave = tid >> 6;
    int col = lane & 15, l4 = lane >> 4;
    int id = blockIdx.x;
    int xcd = id & 7, slot = id >> 3;
    int by = 4 * xcd + (slot & 3);
    int bx = slot >> 2;              // 0..23
    int m0 = by * 128;
    const u16* Bsrc; const float* bias; int n0, mode;
    if (bx < 16)      { mode = 0; Bsrc = Wqb; bias = bq; n0 = bx * 64; }
    else if (bx < 20) { mode = 1; Bsrc = Wkb; bias = bk; n0 = (bx - 16) * 64; }
    else              { mode = 2; Bsrc = Wvb; bias = bv; n0 = (bx - 20) * 64; }

    const u16* ga0 = Xb + (size_t)(m0 + (tid >> 2)) * HIDDEN + (tid & 3) * 8;
    const u16* ga1 = Xb + (size_t)(m0 + 64 + (tid >> 2)) * HIDDEN + (tid & 3) * 8;
    const u16* gb0 = Bsrc + (size_t)(n0 + (tid >> 2)) * HIDDEN + (tid & 3) * 8;
    u16* la0 = &sA[wave * 512];
    u16* la1 = &sA[2048 + wave * 512];
    u16* lb0 = &sB[wave * 512];

    f32x4 acc[2][4];
    #pragma unroll
    for (int i = 0; i < 2; ++i)
        #pragma unroll
        for (int j = 0; j < 4; ++j) acc[i][j] = (f32x4){0.f, 0.f, 0.f, 0.f};
    int mh = wave * 32;

    for (int k0 = 0; k0 < HIDDEN; k0 += 32) {
        __syncthreads();
        async_ld16(ga0, la0); async_ld16(ga1, la1); async_ld16(gb0, lb0);
        ga0 += 32; ga1 += 32; gb0 += 32;
        __syncthreads();
        short8 af[2], bf[4];
        #pragma unroll
        for (int mi = 0; mi < 2; ++mi)
            af[mi] = *(short8*)&sA[(mh + mi * 16 + col) * 32 + l4 * 8];
        #pragma unroll
        for (int ni = 0; ni < 4; ++ni)
            bf[ni] = *(short8*)&sB[(ni * 16 + col) * 32 + l4 * 8];
        #pragma unroll
        for (int mi = 0; mi < 2; ++mi)
            #pragma unroll
            for (int ni = 0; ni < 4; ++ni)
                acc[mi][ni] = __builtin_amdgcn_mfma_f32_16x16x32_bf16(af[mi], bf[ni], acc[mi][ni], 0, 0, 0);
    }

    float bcol[4];
    #pragma unroll
    for (int ni = 0; ni < 4; ++ni) bcol[ni] = bias[n0 + ni * 16 + col];

    if (mode == 2) {
        #pragma unroll
        for (int mi = 0; mi < 2; ++mi) {
            int m = m0 + mh + mi * 16 + l4 * 4;
            int b = m >> 11, s = m & 2047;
            #pragma unroll
            for (int ni = 0; ni < 4; ++ni) {
                int dg = n0 + ni * 16 + col;
                u16x4 pk = {f2bf(acc[mi][ni][0] + bcol[ni]), f2bf(acc[mi][ni][1] + bcol[ni]),
                            f2bf(acc[mi][ni][2] + bcol[ni]), f2bf(acc[mi][ni][3] + bcol[ni])};
                *(u16x4*)&Vtp[((size_t)(b * NKV + (dg >> 6)) * HD + (dg & 63)) * SEQ_ + s] = pk;
            }
        }
    } else {
        int nheads = (mode == 0) ? NH : NKV;
        u16* outp = (mode == 0) ? Qp : Kp;
        float osc = (mode == 0) ? 0.125f * LOG2E : 1.0f;   // fold 1/sqrt(64)*log2e into Q
        int h = n0 >> 6;
        #pragma unroll
        for (int mi = 0; mi < 2; ++mi)
            #pragma unroll
            for (int r = 0; r < 4; ++r) {
                int m = m0 + mh + mi * 16 + l4 * 4 + r;
                int b = m >> 11, s = m & 2047;
                u16* q = outp + ((size_t)(b * nheads + h) * SEQ_ + s) * HD;
                const float2* tb = rtab + (size_t)s * 32;
                #pragma unroll
                for (int p = 0; p < 2; ++p) {
                    float x0 = acc[mi][p][r] + bcol[p];
                    float x1 = acc[mi][p + 2][r] + bcol[p + 2];
                    float2 cs = tb[16 * p + col];
                    q[16 * p + col]      = f2bf((x0 * cs.x - x1 * cs.y) * osc);
                    q[16 * p + col + 32] = f2bf((x0 * cs.y + x1 * cs.x) * osc);
                }
            }
    }
}

// ---------------- Wo MFMA GEMM, 128x64 tile, XCD-affine (R11) ----------------
__global__ __launch_bounds__(256) void gemm_wo(
    const u16* __restrict__ Abf, const u16* __restrict__ Wob, float* __restrict__ out)
{
    __shared__ u16 sA[128 * 32];
    __shared__ u16 sB[64 * 32];
    int tid = threadIdx.x, lane = tid & 63, wave = tid >> 6;
    int col = lane & 15, l4 = lane >> 4;
    int id = blockIdx.x;
    int xcd = id & 7, slot = id >> 3;
    int by = 4 * xcd + (slot & 3);
    int bx = slot >> 2;              // 0..15
    int m0 = by * 128, n0 = bx * 64;
    const u16* ga0 = Abf + (size_t)(m0 + (tid >> 2)) * HIDDEN + (tid & 3) * 8;
    const u16* ga1 = Abf + (size_t)(m0 + 64 + (tid >> 2)) * HIDDEN + (tid & 3) * 8;
    const u16* gb0 = Wob + (size_t)(n0 + (tid >> 2)) * HIDDEN + (tid & 3) * 8;
    u16* la0 = &sA[wave * 512];
    u16* la1 = &sA[2048 + wave * 512];
    u16* lb0 = &sB[wave * 512];

    f32x4 acc[2][4];
    #pragma unroll
    for (int i = 0; i < 2; ++i)
        #pragma unroll
        for (int j = 0; j < 4; ++j) acc[i][j] = (f32x4){0.f, 0.f, 0.f, 0.f};
    int mh = wave * 32;

    for (int k0 = 0; k0 < HIDDEN; k0 += 32) {
        __syncthreads();
        async_ld16(ga0, la0); async_ld16(ga1, la1); async_ld16(gb0, lb0);
        ga0 += 32; ga1 += 32; gb0 += 32;
        __syncthreads();
        short8 af[2], bf[4];
        #pragma unroll
        for (int mi = 0; mi < 2; ++mi)
            af[mi] = *(short8*)&sA[(mh + mi * 16 + col) * 32 + l4 * 8];
        #pragma unroll
        for (int ni = 0; ni < 4; ++ni)
            bf[ni] = *(short8*)&sB[(ni * 16 + col) * 32 + l4 * 8];
        #pragma unroll
        for (int mi = 0; mi < 2; ++mi)
            #pragma unroll
            for (int ni = 0; ni < 4; ++ni)
                acc[mi][ni] = __builtin_amdgcn_mfma_f32_16x16x32_bf16(af[mi], bf[ni], acc[mi][ni], 0, 0, 0);
    }
    #pragma unroll
    for (int mi = 0; mi < 2; ++mi)
        #pragma unroll
        for (int r = 0; r < 4; ++r) {
            int m = m0 + mh + mi * 16 + l4 * 4 + r;
            #pragma unroll
            for (int ni = 0; ni < 4; ++ni)
                out[(size_t)m * HIDDEN + n0 + ni * 16 + col] = acc[mi][ni][r];
        }
}

// ---------------- MFMA flash attention v9: barrier-free wave-autonomous ----------------
// 64 q/WG, 4 waves (ws = wave&1: 32-q slice, kh = wave>>1: 32-key half).
// Each wave stages its OWN 8 KB K/V half-tile (dbuf across two distinct LDS symbols),
// waits with wave-local vmcnt. No __syncthreads in the K-loop.
__global__ __launch_bounds__(256, 2) void attn_mfma(
    const u16* __restrict__ Qp, const u16* __restrict__ Kp,
    const u16* __restrict__ Vtp, const float* __restrict__ ams,
    u16* __restrict__ Abf)
{
    __shared__ u16 smemA[16384];   // per-wave: [wave*4096]: K half [0,2048) V half [2048,4096)
    __shared__ u16 smemB[16384];   // ping-pong partner (distinct symbol -> no alias w/ A reads)
    __shared__ u16 sP[5120];       // per-wave P scratch, stride-40 rows
    int tid = threadIdx.x;
    int lane = tid & 63, wave = tid >> 6;     // 0..3
    int col = lane & 31, h5 = lane >> 5;
    int ws = wave & 1, kh = wave >> 1;
    int qb = blockIdx.x, bh = blockIdx.y;
    int b = bh >> 4, h = bh & 15, hk = h >> 2;
    int q0 = qb * 64;
    int qbase = q0 + ws * 32;
    int qcol = qbase + col;
    int khi = kh * 32;
    u16* pwA = smemA + wave * 4096;
    u16* pwB = smemB + wave * 4096;
    u16* sPw = sP + wave * 1280;

    // Q fragments (B-operand): lane holds Q[q=qbase+col][d = ds*16 + h5*8 + j]
    const u16* qp = Qp + ((size_t)(b * NH + h) * SEQ_ + qbase + col) * HD;
    short8 qf[4];
    #pragma unroll
    for (int ds = 0; ds < 4; ++ds)
        qf[ds] = *(const short8*)(qp + ds * 16 + h5 * 8);

    // per-lane staging sources (XOR-swizzled 16B chunks; K by row&7, V by d&3)
    int rK = lane >> 3;                               // 0..7
    int cK = ((lane & 7) ^ rK) * 8;
    const u16* pKs = Kp + (size_t)(b * NKV + hk) * SEQ_ * HD + (size_t)(khi + rK) * HD + cK;
    int rV = lane >> 2;                               // 0..15
    int cV = ((lane & 3) ^ (rV & 3)) * 8;
    const u16* pVs = Vtp + (size_t)(b * NKV + hk) * HD * SEQ_ + (size_t)rV * SEQ_ + khi + cV;

    f32x16 O[2];
    #pragma unroll
    for (int dt = 0; dt < 2; ++dt)
        #pragma unroll
        for (int e = 0; e < 16; ++e) O[dt][e] = 0.f;
    float lsum = 0.f;

    const float* ampw = ams + b * SEQ_ + khi + 4 * h5;
    int nk = min(SEQ_, q0 + 64 + WIN);
    int nkb = (nk + 63) >> 6;
    int nkbw = min(nkb, ((qbase + 31 + WIN - khi) >> 6) + 1);   // this wave's live tiles

    auto stage = [&](u16* dst, int k0) {
        #pragma unroll
        for (int i = 0; i < 4; ++i) {
            async_ld16(pKs + (size_t)(k0 + i * 8) * HD, dst + i * 512);
            async_ld16(pVs + (size_t)(i * 16) * SEQ_ + k0, dst + 2048 + i * 512);
        }
    };
    auto compute = [&](const u16* sK, const u16* sVT, int k0) {
        f32x16 St;
        #pragma unroll
        for (int e = 0; e < 16; ++e) St[e] = 0.f;
        #pragma unroll
        for (int ds = 0; ds < 4; ++ds) {
            short8 kf = *(short8*)&sK[col * 64 + (((ds * 2 + h5) ^ (col & 7)) * 8)];
            St = __builtin_amdgcn_mfma_f32_32x32x16_bf16(kf, qf[ds], St, 0, 0, 0);
        }
        bool full = (k0 + khi + 31) <= (qbase + WIN);   // wave-uniform
        float ps = 0.f;
        #pragma unroll
        for (int g = 0; g < 4; ++g) {
            int krow = 8 * g + 4 * h5;
            float4 amv = *(const float4*)(ampw + k0 + 8 * g);
            float amr[4] = {amv.x, amv.y, amv.z, amv.w};
            float pe[4];
            #pragma unroll
            for (int i = 0; i < 4; ++i) {
                float s = St[g * 4 + i] + amr[i];
                if (!full) {
                    int kg = k0 + khi + krow + i;
                    s = (kg - qcol <= WIN) ? s : -INFINITY;
                }
                float e = __builtin_amdgcn_exp2f(s);   // scores pre-scaled by log2e
                pe[i] = e;
                ps += e;
            }
            uint2 w;
            w.x = pk_trunc(pe[0], pe[1]);
            w.y = pk_trunc(pe[2], pe[3]);
            *(uint2*)&sPw[col * 40 + g * 8 + 4 * h5] = w;
        }
        lsum += ps;
        short8 pb0 = *(short8*)&sPw[col * 40 + h5 * 8];
        short8 pb1 = *(short8*)&sPw[col * 40 + (2 + h5) * 8];
        #pragma unroll
        for (int dt = 0; dt < 2; ++dt) {
            short8 vf0 = *(short8*)&sVT[(dt * 32 + col) * 32 + ((h5 ^ (col & 3)) * 8)];
            O[dt] = __builtin_amdgcn_mfma_f32_32x32x16_bf16(vf0, pb0, O[dt], 0, 0, 0);
            short8 vf1 = *(short8*)&sVT[(dt * 32 + col) * 32 + (((2 + h5) ^ (col & 3)) * 8)];
            O[dt] = __builtin_amdgcn_mfma_f32_32x32x16_bf16(vf1, pb1, O[dt], 0, 0, 0);
        }
    };

    stage(pwA, 0);                    // tile 0 -> A
    for (int kb = 0; kb < nkbw; ++kb) {
        int k0 = kb * 64;
        bool even = (kb & 1) == 0;
        u16* cur = even ? pwA : pwB;
        u16* nxt = even ? pwB : pwA;
        if (kb + 1 < nkbw) {
            stage(nxt, k0 + 64);
            WAITVM(8);                // tile kb landed; kb+1's 8 DMAs in flight
        } else {
            WAITVM(0);
        }
        compute(cur, cur + 2048, k0);
    }
    WAITVM(0);                        // drain before smem reuse

    // ---- combine key-halves (kh=0 <- kh=1) through LDS overlay ----
    float l = lsum + __shfl_xor(lsum, 32);   // full 32-key partial for q = col
    __syncthreads();
    float* sO = (float*)smemA;               // [ws*32+col][68]: 64 d f32 + lsum at [64]
    int rq = ws * 32 + col;
    if (kh == 1) {
        #pragma unroll
        for (int dt = 0; dt < 2; ++dt)
            #pragma unroll
            for (int g = 0; g < 4; ++g) {
                float4 v = make_float4(O[dt][g * 4 + 0], O[dt][g * 4 + 1],
                                       O[dt][g * 4 + 2], O[dt][g * 4 + 3]);
                *(float4*)&sO[rq * 68 + dt * 32 + 8 * g + 4 * h5] = v;
            }
        if (h5 == 0) sO[rq * 68 + 64] = l;
    }
    __syncthreads();
    if (kh == 0) {
        float linv = 1.0f / (l + sO[rq * 68 + 64]);
        u16* op = Abf + (size_t)(b * SEQ_ + qbase + col) * HIDDEN + h * HD;
        #pragma unroll
        for (int dt = 0; dt < 2; ++dt)
            #pragma unroll
            for (int g = 0; g < 4; ++g) {
                float4 v = *(float4*)&sO[rq * 68 + dt * 32 + 8 * g + 4 * h5];
                u16x4 pk = {f2bf((O[dt][g * 4 + 0] + v.x) * linv),
                            f2bf((O[dt][g * 4 + 1] + v.y) * linv),
                            f2bf((O[dt][g * 4 + 2] + v.z) * linv),
                            f2bf((O[dt][g * 4 + 3] + v.w) * linv)};
                *(u16x4*)(op + dt * 32 + 8 * g + 4 * h5) = pk;
            }
    }
}

extern "C" void kernel_launch(void* const* d_in, const int* in_sizes, int n_in,
                              void* d_out, int out_size, void* d_ws, size_t ws_size,
                              hipStream_t stream) {
    const float* X  = (const float*)d_in[0];
    const float* am = (const float*)d_in[1];
    const float* Wq = (const float*)d_in[2];
    const float* bq = (const float*)d_in[3];
    const float* Wk = (const float*)d_in[4];
    const float* bk = (const float*)d_in[5];
    const float* Wv = (const float*)d_in[6];
    const float* bv = (const float*)d_in[7];
    const float* Wo = (const float*)d_in[8];
    float* out = (float*)d_out;

    const int M = BS_ * SEQ_;            // 4096
    u16* Qp  = (u16*)d_ws;                         // 8 MB
    u16* Kp  = Qp + (size_t)M * HIDDEN;            // 2 MB
    u16* Vtp = Kp + (size_t)M * 256;               // 2 MB
    u16* Xb  = Vtp + (size_t)M * 256;              // 8 MB
    u16* Wqb = Xb + (size_t)M * HIDDEN;            // 2 MB
    u16* Wkb = Wqb + (size_t)HIDDEN * HIDDEN;      // 0.5 MB
    u16* Wvb = Wkb + (size_t)256 * HIDDEN;         // 0.5 MB
    u16* Wob = Wvb + (size_t)256 * HIDDEN;         // 2 MB
    float* ams = (float*)(Wob + (size_t)HIDDEN * HIDDEN);  // 16 KB
    float2* rtab = (float2*)(ams + BS_ * SEQ_);            // 512 KB RoPE LUT
    u16* Abf = Xb;  // alias: Xb consumed by gemm_qkv before attn writes Abf

    dim3 blk(256);
    cast6<<<dim3(6916), blk, 0, stream>>>(X, Wq, Wk, Wv, Wo, am, Xb, Wqb, Wkb, Wvb, Wob, ams, rtab);
    gemm_qkv<<<dim3(768), blk, 0, stream>>>(Xb, Wqb, Wkb, Wvb, bq, bk, bv, rtab, Qp, Kp, Vtp);
    attn_mfma<<<dim3(SEQ_ / 64, BS_ * NH), blk, 0, stream>>>(Qp, Kp, Vtp, ams, Abf);
    gemm_wo<<<dim3(512), blk, 0, stream>>>(Abf, Wob, out);
}

// Round 14
// 197.381 us; speedup vs baseline: 1.0755x; 1.0755x over previous
//
#include <hip/hip_runtime.h>
#include <math.h>

#define HIDDEN 1024
#define NH 16
#define NKV 4
#define HD 64
#define BS_ 2
#define SEQ_ 2048
#define WIN 1534   // allowed iff k - q <= 1534
#define LOG2E 1.4426950408889634f

typedef unsigned short u16;
typedef short short8 __attribute__((ext_vector_type(8)));
typedef float f32x4 __attribute__((ext_vector_type(4)));
typedef float f32x16 __attribute__((ext_vector_type(16)));
typedef u16 u16x4 __attribute__((ext_vector_type(4)));

// s_waitcnt: vmcnt low[3:0], expcnt[6:4]=7 (no wait), lgkmcnt[12:8]=31 (no wait)
#define WAITVM(n) __builtin_amdgcn_s_waitcnt(0x1f70 | (n))

__device__ __forceinline__ u16 f2bf(float f) {
    unsigned u = __float_as_uint(f);
    u += 0x7fff + ((u >> 16) & 1);      // RNE
    return (u16)(u >> 16);
}

// pack two f32 -> two bf16 (truncation) in ONE v_perm_b32
__device__ __forceinline__ unsigned pk_trunc(float lo, float hi) {
    return __builtin_amdgcn_perm(__float_as_uint(hi), __float_as_uint(lo), 0x07060302u);
}

__device__ __forceinline__ void async_ld16(const u16* g, u16* l) {
    __builtin_amdgcn_global_load_lds(
        (const __attribute__((address_space(1))) unsigned int*)g,
        (__attribute__((address_space(3))) unsigned int*)l, 16, 0, 0);
}

// -------- cast fp32 -> bf16 (X + 4 weights), pre-scale amask, build RoPE LUT --------
#define C_X  1048576
#define C_WQ 1310720
#define C_WK 1376256
#define C_WV 1441792
#define C_WO 1703936
#define C_AM 1704960
__global__ __launch_bounds__(256) void cast6(
    const float* __restrict__ x, const float* __restrict__ wq,
    const float* __restrict__ wk, const float* __restrict__ wv,
    const float* __restrict__ wo, const float* __restrict__ amask,
    u16* __restrict__ xb, u16* __restrict__ wqb, u16* __restrict__ wkb,
    u16* __restrict__ wvb, u16* __restrict__ wob, float* __restrict__ ams,
    float2* __restrict__ rtab)
{
    if (blockIdx.x >= 6660) {
        int i = (blockIdx.x - 6660) * 256 + threadIdx.x;   // (s, j) over 2048 x 32
        int s = i >> 5, j = i & 31;
        float inv = powf(10000.0f, -(float)j * (1.0f / 32.0f));
        float sn, cs;
        sincosf((float)s * inv, &sn, &cs);
        rtab[i] = make_float2(cs, sn);
        return;
    }
    int c = blockIdx.x * 256 + threadIdx.x;   // 4-elem chunk id
    const float* src; u16* dst; int base;
    if (c < C_X)       { src = x;  dst = xb;  base = 0; }
    else if (c < C_WQ) { src = wq; dst = wqb; base = C_X; }
    else if (c < C_WK) { src = wk; dst = wkb; base = C_WQ; }
    else if (c < C_WV) { src = wv; dst = wvb; base = C_WK; }
    else if (c < C_WO) { src = wo; dst = wob; base = C_WV; }
    else {
        int i = (c - C_WO) * 4;
        const float sc = -10000.0f * LOG2E;
        float4 v = *(const float4*)(amask + i);
        *(float4*)(ams + i) = make_float4(v.x * sc, v.y * sc, v.z * sc, v.w * sc);
        return;
    }
    int i = (c - base) * 4;
    float4 v = *(const float4*)(src + i);
    u16x4 o = {f2bf(v.x), f2bf(v.y), f2bf(v.z), f2bf(v.w)};
    *(u16x4*)(dst + i) = o;
}

// ---------------- fused QKV MFMA GEMM: wave-autonomous, barrier-free ----------------
// 768 blocks 1-D, XCD-affine (xcd = id&7 owns 4 m-row blocks x all 24 bx).
// Each wave owns 32 A-rows + a private copy of the 64-col B tile, dbuf in LDS,
// synchronized per-wave with vmcnt. No __syncthreads anywhere.
__global__ __launch_bounds__(256) void gemm_qkv(
    const u16* __restrict__ Xb, const u16* __restrict__ Wqb,
    const u16* __restrict__ Wkb, const u16* __restrict__ Wvb,
    const float* __restrict__ bq, const float* __restrict__ bk,
    const float* __restrict__ bv, const float2* __restrict__ rtab,
    u16* __restrict__ Qp, u16* __restrict__ Kp, u16* __restrict__ Vtp)
{
    __shared__ u16 smem[4][2][3072];   // [wave][buf][A 1024 | B 2048] = 48 KB
    int tid = threadIdx.x, lane = tid & 63, wave = tid >> 6;
    int col = lane & 15, l4 = lane >> 4;
    int id = blockIdx.x;
    int xcd = id & 7, slot = id >> 3;
    int by = 4 * xcd + (slot & 3);
    int bx = slot >> 2;              // 0..23
    int m0 = by * 128;
    const u16* Bsrc; const float* bias; int n0, mode;
    if (bx < 16)      { mode = 0; Bsrc = Wqb; bias = bq; n0 = bx * 64; }
    else if (bx < 20) { mode = 1; Bsrc = Wkb; bias = bk; n0 = (bx - 16) * 64; }
    else              { mode = 2; Bsrc = Wvb; bias = bv; n0 = (bx - 20) * 64; }
    int mh = wave * 32;

    // per-lane staging sources: chunk c -> row c>>2, kchunk c&3 (identity dest layout)
    const u16* ga0 = Xb + (size_t)(m0 + mh + (lane >> 2)) * HIDDEN + (lane & 3) * 8;
    const u16* ga1 = ga0 + (size_t)16 * HIDDEN;
    const u16* gb0 = Bsrc + (size_t)(n0 + (lane >> 2)) * HIDDEN + (lane & 3) * 8;
    const u16* gb1 = gb0 + (size_t)16 * HIDDEN;
    const u16* gb2 = gb0 + (size_t)32 * HIDDEN;
    const u16* gb3 = gb0 + (size_t)48 * HIDDEN;

    f32x4 acc[2][4];
    #pragma unroll
    for (int i = 0; i < 2; ++i)
        #pragma unroll
        for (int j = 0; j < 4; ++j) acc[i][j] = (f32x4){0.f, 0.f, 0.f, 0.f};

    // prologue: tile 0 -> buf 0 (6 DMAs)
    {
        u16* d = &smem[wave][0][0];
        async_ld16(ga0, d);            async_ld16(ga1, d + 512);
        async_ld16(gb0, d + 1024);     async_ld16(gb1, d + 1536);
        async_ld16(gb2, d + 2048);     async_ld16(gb3, d + 2560);
    }

    for (int it = 0; it < 32; ++it) {
        int buf = it & 1;
        if (it + 1 < 32) {
            int k = (it + 1) * 32;
            u16* d = &smem[wave][buf ^ 1][0];
            async_ld16(ga0 + k, d);          async_ld16(ga1 + k, d + 512);
            async_ld16(gb0 + k, d + 1024);   async_ld16(gb1 + k, d + 1536);
            async_ld16(gb2 + k, d + 2048);   async_ld16(gb3 + k, d + 2560);
            WAITVM(6);    // tile `it` landed; tile it+1's 6 DMAs in flight
        } else {
            WAITVM(0);
        }
        const u16* d = &smem[wave][buf][0];
        short8 af[2], bf[4];
        #pragma unroll
        for (int mi = 0; mi < 2; ++mi)
            af[mi] = *(short8*)&d[(mi * 16 + col) * 32 + l4 * 8];
        #pragma unroll
        for (int ni = 0; ni < 4; ++ni)
            bf[ni] = *(short8*)&d[1024 + (ni * 16 + col) * 32 + l4 * 8];
        #pragma unroll
        for (int mi = 0; mi < 2; ++mi)
            #pragma unroll
            for (int ni = 0; ni < 4; ++ni)
                acc[mi][ni] = __builtin_amdgcn_mfma_f32_16x16x32_bf16(af[mi], bf[ni], acc[mi][ni], 0, 0, 0);
    }

    float bcol[4];
    #pragma unroll
    for (int ni = 0; ni < 4; ++ni) bcol[ni] = bias[n0 + ni * 16 + col];

    if (mode == 2) {
        // V^T bf16: [b][hk][d][SEQ]; s contiguous over r -> b64 stores
        #pragma unroll
        for (int mi = 0; mi < 2; ++mi) {
            int m = m0 + mh + mi * 16 + l4 * 4;
            int b = m >> 11, s = m & 2047;
            #pragma unroll
            for (int ni = 0; ni < 4; ++ni) {
                int dg = n0 + ni * 16 + col;
                u16x4 pk = {f2bf(acc[mi][ni][0] + bcol[ni]), f2bf(acc[mi][ni][1] + bcol[ni]),
                            f2bf(acc[mi][ni][2] + bcol[ni]), f2bf(acc[mi][ni][3] + bcol[ni])};
                *(u16x4*)&Vtp[((size_t)(b * NKV + (dg >> 6)) * HD + (dg & 63)) * SEQ_ + s] = pk;
            }
        }
    } else {
        int nheads = (mode == 0) ? NH : NKV;
        u16* outp = (mode == 0) ? Qp : Kp;
        float osc = (mode == 0) ? 0.125f * LOG2E : 1.0f;   // fold 1/sqrt(64)*log2e into Q
        int h = n0 >> 6;
        #pragma unroll
        for (int mi = 0; mi < 2; ++mi)
            #pragma unroll
            for (int r = 0; r < 4; ++r) {
                int m = m0 + mh + mi * 16 + l4 * 4 + r;
                int b = m >> 11, s = m & 2047;
                u16* q = outp + ((size_t)(b * nheads + h) * SEQ_ + s) * HD;
                const float2* tb = rtab + (size_t)s * 32;
                #pragma unroll
                for (int p = 0; p < 2; ++p) {
                    float x0 = acc[mi][p][r] + bcol[p];
                    float x1 = acc[mi][p + 2][r] + bcol[p + 2];
                    float2 cs = tb[16 * p + col];
                    q[16 * p + col]      = f2bf((x0 * cs.x - x1 * cs.y) * osc);
                    q[16 * p + col + 32] = f2bf((x0 * cs.y + x1 * cs.x) * osc);
                }
            }
    }
}

// ---------------- Wo MFMA GEMM: wave-autonomous, barrier-free ----------------
// 512 blocks 1-D, XCD-affine.
__global__ __launch_bounds__(256) void gemm_wo(
    const u16* __restrict__ Abf, const u16* __restrict__ Wob, float* __restrict__ out)
{
    __shared__ u16 smem[4][2][3072];   // 48 KB
    int tid = threadIdx.x, lane = tid & 63, wave = tid >> 6;
    int col = lane & 15, l4 = lane >> 4;
    int id = blockIdx.x;
    int xcd = id & 7, slot = id >> 3;
    int by = 4 * xcd + (slot & 3);
    int bx = slot >> 2;              // 0..15
    int m0 = by * 128, n0 = bx * 64;
    int mh = wave * 32;

    const u16* ga0 = Abf + (size_t)(m0 + mh + (lane >> 2)) * HIDDEN + (lane & 3) * 8;
    const u16* ga1 = ga0 + (size_t)16 * HIDDEN;
    const u16* gb0 = Wob + (size_t)(n0 + (lane >> 2)) * HIDDEN + (lane & 3) * 8;
    const u16* gb1 = gb0 + (size_t)16 * HIDDEN;
    const u16* gb2 = gb0 + (size_t)32 * HIDDEN;
    const u16* gb3 = gb0 + (size_t)48 * HIDDEN;

    f32x4 acc[2][4];
    #pragma unroll
    for (int i = 0; i < 2; ++i)
        #pragma unroll
        for (int j = 0; j < 4; ++j) acc[i][j] = (f32x4){0.f, 0.f, 0.f, 0.f};

    {
        u16* d = &smem[wave][0][0];
        async_ld16(ga0, d);            async_ld16(ga1, d + 512);
        async_ld16(gb0, d + 1024);     async_ld16(gb1, d + 1536);
        async_ld16(gb2, d + 2048);     async_ld16(gb3, d + 2560);
    }

    for (int it = 0; it < 32; ++it) {
        int buf = it & 1;
        if (it + 1 < 32) {
            int k = (it + 1) * 32;
            u16* d = &smem[wave][buf ^ 1][0];
            async_ld16(ga0 + k, d);          async_ld16(ga1 + k, d + 512);
            async_ld16(gb0 + k, d + 1024);   async_ld16(gb1 + k, d + 1536);
            async_ld16(gb2 + k, d + 2048);   async_ld16(gb3 + k, d + 2560);
            WAITVM(6);
        } else {
            WAITVM(0);
        }
        const u16* d = &smem[wave][buf][0];
        short8 af[2], bf[4];
        #pragma unroll
        for (int mi = 0; mi < 2; ++mi)
            af[mi] = *(short8*)&d[(mi * 16 + col) * 32 + l4 * 8];
        #pragma unroll
        for (int ni = 0; ni < 4; ++ni)
            bf[ni] = *(short8*)&d[1024 + (ni * 16 + col) * 32 + l4 * 8];
        #pragma unroll
        for (int mi = 0; mi < 2; ++mi)
            #pragma unroll
            for (int ni = 0; ni < 4; ++ni)
                acc[mi][ni] = __builtin_amdgcn_mfma_f32_16x16x32_bf16(af[mi], bf[ni], acc[mi][ni], 0, 0, 0);
    }
    #pragma unroll
    for (int mi = 0; mi < 2; ++mi)
        #pragma unroll
        for (int r = 0; r < 4; ++r) {
            int m = m0 + mh + mi * 16 + l4 * 4 + r;
            #pragma unroll
            for (int ni = 0; ni < 4; ++ni)
                out[(size_t)m * HIDDEN + n0 + ni * 16 + col] = acc[mi][ni][r];
        }
}

// ---------------- MFMA flash attention v7.1 (R11 exact): 32x32x16, 64 q/WG ----------------
// Grid (32, 32) = 1024 WGs -> 4 WG/CU, 16 waves/CU.
// Wave (ws = wave&1: 32-q slice, kh = wave>>1: 32-key half).
__global__ __launch_bounds__(256, 4) void attn_mfma(
    const u16* __restrict__ Qp, const u16* __restrict__ Kp,
    const u16* __restrict__ Vtp, const float* __restrict__ ams,
    u16* __restrict__ Abf)
{
    __shared__ u16 smem[13312];      // sK[0:4096] sVT[4096:8192] sP[8192:13312]
    u16* sK = smem;
    u16* sVT = smem + 4096;
    int tid = threadIdx.x;
    int lane = tid & 63, wave = tid >> 6;     // 0..3
    int col = lane & 31, h5 = lane >> 5;
    int sx = col & 7;
    int ws = wave & 1, kh = wave >> 1;
    int qb = blockIdx.x, bh = blockIdx.y;
    int b = bh >> 4, h = bh & 15, hk = h >> 2;
    int q0 = qb * 64;
    int qbase = q0 + ws * 32;                 // this wave's 32 queries
    int qcol = qbase + col;
    u16* sPw = smem + 8192 + wave * 1280;     // [q=col][32 keys], row stride 40 u16

    // Q fragments (B-operand): lane holds Q[q=qbase+col][d = ds*16 + h5*8 + j]
    const u16* qp = Qp + ((size_t)(b * NH + h) * SEQ_ + qbase + col) * HD;
    short8 qf[4];
    #pragma unroll
    for (int ds = 0; ds < 4; ++ds)
        qf[ds] = *(const short8*)(qp + ds * 16 + h5 * 8);

    // staging: 256 threads x 16B x 2 rounds each for K and V, XOR-swizzled chunks
    int srow = tid >> 3;
    int swc = ((tid & 7) ^ (srow & 7)) * 8;
    const u16* pK0 = Kp + (size_t)(b * NKV + hk) * SEQ_ * HD + (size_t)srow * HD + swc;
    const u16* pK1 = pK0 + 32 * HD;
    const u16* pV0 = Vtp + (size_t)(b * NKV + hk) * HD * SEQ_ + (size_t)srow * SEQ_ + swc;
    const u16* pV1 = pV0 + 32 * SEQ_;
    u16* dK0 = &sK[wave * 512];
    u16* dK1 = &sK[2048 + wave * 512];
    u16* dV0 = &sVT[wave * 512];
    u16* dV1 = &sVT[2048 + wave * 512];

    f32x16 O[2];
    #pragma unroll
    for (int dt = 0; dt < 2; ++dt)
        #pragma unroll
        for (int e = 0; e < 16; ++e) O[dt][e] = 0.f;
    float lsum = 0.f;

    const float* ampw = ams + b * SEQ_ + kh * 32 + 4 * h5;
    int nk = min(SEQ_, q0 + 64 + WIN);
    int nkb = (nk + 63) >> 6;

    for (int kb = 0; kb < nkb; ++kb) {
        int k0 = kb * 64;
        __syncthreads();   // prior tile's reads complete
        async_ld16(pK0, dK0);
        async_ld16(pK1, dK1);
        async_ld16(pV0, dV0);
        async_ld16(pV1, dV1);
        pK0 += 64 * HD; pK1 += 64 * HD; pV0 += 64; pV1 += 64;
        __syncthreads();   // DMA landed

        bool dead = (k0 + kh * 32) > (qbase + 31 + WIN);   // wave-uniform
        if (!dead) {
            f32x16 St;
            #pragma unroll
            for (int e = 0; e < 16; ++e) St[e] = 0.f;
            #pragma unroll
            for (int ds = 0; ds < 4; ++ds) {
                short8 kf = *(short8*)&sK[(kh * 32 + col) * 64 + ((ds * 2 + h5) ^ sx) * 8];
                St = __builtin_amdgcn_mfma_f32_32x32x16_bf16(kf, qf[ds], St, 0, 0, 0);
            }
            bool full = (k0 + kh * 32 + 31) <= (qbase + WIN);   // wave-uniform
            float ps = 0.f;
            #pragma unroll
            for (int g = 0; g < 4; ++g) {
                int krow = 8 * g + 4 * h5;
                float4 amv = *(const float4*)(ampw + 8 * g);
                float amr[4] = {amv.x, amv.y, amv.z, amv.w};
                float pe[4];
                #pragma unroll
                for (int i = 0; i < 4; ++i) {
                    float s = St[g * 4 + i] + amr[i];
                    if (!full) {
                        int kg = k0 + kh * 32 + krow + i;
                        s = (kg - qcol <= WIN) ? s : -INFINITY;
                    }
                    float e = __builtin_amdgcn_exp2f(s);   // scores pre-scaled by log2e
                    pe[i] = e;
                    ps += e;
                }
                uint2 w;
                w.x = pk_trunc(pe[0], pe[1]);
                w.y = pk_trunc(pe[2], pe[3]);
                *(uint2*)&sPw[col * 40 + g * 8 + 4 * h5] = w;   // keys 8g+4h5..+3
            }
            lsum += ps;
            // P^T B-frags: lane holds P[q=col][key = kstep*16 + h5*8 + j]
            short8 pb0 = *(short8*)&sPw[col * 40 + (0 * 2 + h5) * 8];
            short8 pb1 = *(short8*)&sPw[col * 40 + (1 * 2 + h5) * 8];
            #pragma unroll
            for (int dt = 0; dt < 2; ++dt) {
                short8 vf0 = *(short8*)&sVT[(dt * 32 + col) * 64 + ((kh * 4 + 0 + h5) ^ sx) * 8];
                O[dt] = __builtin_amdgcn_mfma_f32_32x32x16_bf16(vf0, pb0, O[dt], 0, 0, 0);
                short8 vf1 = *(short8*)&sVT[(dt * 32 + col) * 64 + ((kh * 4 + 2 + h5) ^ sx) * 8];
                O[dt] = __builtin_amdgcn_mfma_f32_32x32x16_bf16(vf1, pb1, O[dt], 0, 0, 0);
            }
        }
        ampw += 64;
    }

    // ---- combine key-halves (kh=0 <- kh=1) through LDS overlay ----
    float l = lsum + __shfl_xor(lsum, 32);   // full 32-key partial for q = col
    __syncthreads();                          // loop reads done; smem reusable
    float* sO = (float*)smem;                 // [ws*32+col][68]: 64 d f32 + lsum at [64]
    int rq = ws * 32 + col;
    if (kh == 1) {
        #pragma unroll
        for (int dt = 0; dt < 2; ++dt)
            #pragma unroll
            for (int g = 0; g < 4; ++g) {
                float4 v = make_float4(O[dt][g * 4 + 0], O[dt][g * 4 + 1],
                                       O[dt][g * 4 + 2], O[dt][g * 4 + 3]);
                *(float4*)&sO[rq * 68 + dt * 32 + 8 * g + 4 * h5] = v;
            }
        if (h5 == 0) sO[rq * 68 + 64] = l;
    }
    __syncthreads();
    if (kh == 0) {
        float linv = 1.0f / (l + sO[rq * 68 + 64]);
        u16* op = Abf + (size_t)(b * SEQ_ + qbase + col) * HIDDEN + h * HD;
        #pragma unroll
        for (int dt = 0; dt < 2; ++dt)
            #pragma unroll
            for (int g = 0; g < 4; ++g) {
                float4 v = *(float4*)&sO[rq * 68 + dt * 32 + 8 * g + 4 * h5];
                u16x4 pk = {f2bf((O[dt][g * 4 + 0] + v.x) * linv),
                            f2bf((O[dt][g * 4 + 1] + v.y) * linv),
                            f2bf((O[dt][g * 4 + 2] + v.z) * linv),
                            f2bf((O[dt][g * 4 + 3] + v.w) * linv)};
                *(u16x4*)(op + dt * 32 + 8 * g + 4 * h5) = pk;
            }
    }
}

extern "C" void kernel_launch(void* const* d_in, const int* in_sizes, int n_in,
                              void* d_out, int out_size, void* d_ws, size_t ws_size,
                              hipStream_t stream) {
    const float* X  = (const float*)d_in[0];
    const float* am = (const float*)d_in[1];
    const float* Wq = (const float*)d_in[2];
    const float* bq = (const float*)d_in[3];
    const float* Wk = (const float*)d_in[4];
    const float* bk = (const float*)d_in[5];
    const float* Wv = (const float*)d_in[6];
    const float* bv = (const float*)d_in[7];
    const float* Wo = (const float*)d_in[8];
    float* out = (float*)d_out;

    const int M = BS_ * SEQ_;            // 4096
    u16* Qp  = (u16*)d_ws;                         // 8 MB
    u16* Kp  = Qp + (size_t)M * HIDDEN;            // 2 MB
    u16* Vtp = Kp + (size_t)M * 256;               // 2 MB
    u16* Xb  = Vtp + (size_t)M * 256;              // 8 MB
    u16* Wqb = Xb + (size_t)M * HIDDEN;            // 2 MB
    u16* Wkb = Wqb + (size_t)HIDDEN * HIDDEN;      // 0.5 MB
    u16* Wvb = Wkb + (size_t)256 * HIDDEN;         // 0.5 MB
    u16* Wob = Wvb + (size_t)256 * HIDDEN;         // 2 MB
    float* ams = (float*)(Wob + (size_t)HIDDEN * HIDDEN);  // 16 KB
    float2* rtab = (float2*)(ams + BS_ * SEQ_);            // 512 KB RoPE LUT
    u16* Abf = Xb;  // alias: Xb consumed by gemm_qkv before attn writes Abf

    dim3 blk(256);
    cast6<<<dim3(6916), blk, 0, stream>>>(X, Wq, Wk, Wv, Wo, am, Xb, Wqb, Wkb, Wvb, Wob, ams, rtab);
    gemm_qkv<<<dim3(768), blk, 0, stream>>>(Xb, Wqb, Wkb, Wvb, bq, bk, bv, rtab, Qp, Kp, Vtp);
    attn_mfma<<<dim3(SEQ_ / 64, BS_ * NH), blk, 0, stream>>>(Qp, Kp, Vtp, ams, Abf);
    gemm_wo<<<dim3(512), blk, 0, stream>>>(Abf, Wob, out);
}

// Round 15
// 184.425 us; speedup vs baseline: 1.1510x; 1.0703x over previous
//
#include <hip/hip_runtime.h>
#include <math.h>

#define HIDDEN 1024
#define NH 16
#define NKV 4
#define HD 64
#define BS_ 2
#define SEQ_ 2048
#define WIN 1534   // allowed iff k - q <= 1534
#define LOG2E 1.4426950408889634f

typedef unsigned short u16;
typedef short short8 __attribute__((ext_vector_type(8)));
typedef float f32x4 __attribute__((ext_vector_type(4)));
typedef float f32x16 __attribute__((ext_vector_type(16)));
typedef u16 u16x4 __attribute__((ext_vector_type(4)));

// s_waitcnt: vmcnt low[3:0], expcnt[6:4]=7 (no wait), lgkmcnt[12:8]=31 (no wait)
#define WAITVM(n) __builtin_amdgcn_s_waitcnt(0x1f70 | (n))
#define BAR() __builtin_amdgcn_s_barrier()

__device__ __forceinline__ u16 f2bf(float f) {
    unsigned u = __float_as_uint(f);
    u += 0x7fff + ((u >> 16) & 1);      // RNE
    return (u16)(u >> 16);
}

// pack two f32 -> two bf16 (truncation) in ONE v_perm_b32
__device__ __forceinline__ unsigned pk_trunc(float lo, float hi) {
    return __builtin_amdgcn_perm(__float_as_uint(hi), __float_as_uint(lo), 0x07060302u);
}

__device__ __forceinline__ void async_ld16(const u16* g, u16* l) {
    __builtin_amdgcn_global_load_lds(
        (const __attribute__((address_space(1))) unsigned int*)g,
        (__attribute__((address_space(3))) unsigned int*)l, 16, 0, 0);
}

// -------- cast fp32 -> bf16 (X + 4 weights), pre-scale amask, build RoPE LUT --------
#define C_X  1048576
#define C_WQ 1310720
#define C_WK 1376256
#define C_WV 1441792
#define C_WO 1703936
#define C_AM 1704960
__global__ __launch_bounds__(256) void cast6(
    const float* __restrict__ x, const float* __restrict__ wq,
    const float* __restrict__ wk, const float* __restrict__ wv,
    const float* __restrict__ wo, const float* __restrict__ amask,
    u16* __restrict__ xb, u16* __restrict__ wqb, u16* __restrict__ wkb,
    u16* __restrict__ wvb, u16* __restrict__ wob, float* __restrict__ ams,
    float2* __restrict__ rtab)
{
    if (blockIdx.x >= 6660) {
        int i = (blockIdx.x - 6660) * 256 + threadIdx.x;   // (s, j) over 2048 x 32
        int s = i >> 5, j = i & 31;
        float inv = powf(10000.0f, -(float)j * (1.0f / 32.0f));
        float sn, cs;
        sincosf((float)s * inv, &sn, &cs);
        rtab[i] = make_float2(cs, sn);
        return;
    }
    int c = blockIdx.x * 256 + threadIdx.x;   // 4-elem chunk id
    const float* src; u16* dst; int base;
    if (c < C_X)       { src = x;  dst = xb;  base = 0; }
    else if (c < C_WQ) { src = wq; dst = wqb; base = C_X; }
    else if (c < C_WK) { src = wk; dst = wkb; base = C_WQ; }
    else if (c < C_WV) { src = wv; dst = wvb; base = C_WK; }
    else if (c < C_WO) { src = wo; dst = wob; base = C_WV; }
    else {
        int i = (c - C_WO) * 4;
        const float sc = -10000.0f * LOG2E;
        float4 v = *(const float4*)(amask + i);
        *(float4*)(ams + i) = make_float4(v.x * sc, v.y * sc, v.z * sc, v.w * sc);
        return;
    }
    int i = (c - base) * 4;
    float4 v = *(const float4*)(src + i);
    u16x4 o = {f2bf(v.x), f2bf(v.y), f2bf(v.z), f2bf(v.w)};
    *(u16x4*)(dst + i) = o;
}

// ---------------- fused QKV MFMA GEMM, 128x64 tile, XCD-affine, drain-free pipeline ----------------
// 768 blocks 1-D: xcd = id&7 owns 4 m-row blocks x all 24 bx.
// K-loop: raw s_barrier pair + per-wave WAITVM(3); no vmcnt(0) inside the loop.
__global__ __launch_bounds__(256) void gemm_qkv(
    const u16* __restrict__ Xb, const u16* __restrict__ Wqb,
    const u16* __restrict__ Wkb, const u16* __restrict__ Wvb,
    const float* __restrict__ bq, const float* __restrict__ bk,
    const float* __restrict__ bv, const float2* __restrict__ rtab,
    u16* __restrict__ Qp, u16* __restrict__ Kp, u16* __restrict__ Vtp)
{
    __shared__ __align__(16) u16 sA[2][4096];   // 16 KB
    __shared__ __align__(16) u16 sB[2][2048];   // 8 KB
    int tid = threadIdx.x, lane = tid & 63, wave = tid >> 6;
    int col = lane & 15, l4 = lane >> 4;
    int id = blockIdx.x;
    int xcd = id & 7, slot = id >> 3;
    int by = 4 * xcd + (slot & 3);
    int bx = slot >> 2;              // 0..23
    int m0 = by * 128;
    const u16* Bsrc; const float* bias; int n0, mode;
    if (bx < 16)      { mode = 0; Bsrc = Wqb; bias = bq; n0 = bx * 64; }
    else if (bx < 20) { mode = 1; Bsrc = Wkb; bias = bk; n0 = (bx - 16) * 64; }
    else              { mode = 2; Bsrc = Wvb; bias = bv; n0 = (bx - 20) * 64; }

    const u16* ga0 = Xb + (size_t)(m0 + (tid >> 2)) * HIDDEN + (tid & 3) * 8;
    const u16* ga1 = Xb + (size_t)(m0 + 64 + (tid >> 2)) * HIDDEN + (tid & 3) * 8;
    const u16* gb0 = Bsrc + (size_t)(n0 + (tid >> 2)) * HIDDEN + (tid & 3) * 8;

    f32x4 acc[2][4];
    #pragma unroll
    for (int i = 0; i < 2; ++i)
        #pragma unroll
        for (int j = 0; j < 4; ++j) acc[i][j] = (f32x4){0.f, 0.f, 0.f, 0.f};
    int mh = wave * 32;

    // prologue: tile 0 -> buf 0
    async_ld16(ga0, &sA[0][wave * 512]);
    async_ld16(ga1, &sA[0][2048 + wave * 512]);
    async_ld16(gb0, &sB[0][wave * 512]);
    ga0 += 32; ga1 += 32; gb0 += 32;

    for (int it = 0; it < 32; ++it) {
        int buf = it & 1;
        BAR();                       // readers of buf^1 (iter it-1) done
        if (it + 1 < 32) {
            int nb = buf ^ 1;
            async_ld16(ga0, &sA[nb][wave * 512]);
            async_ld16(ga1, &sA[nb][2048 + wave * 512]);
            async_ld16(gb0, &sB[nb][wave * 512]);
            ga0 += 32; ga1 += 32; gb0 += 32;
            WAITVM(3);               // my tile-`it` DMAs landed; next tile's stay in flight
        } else {
            WAITVM(0);
        }
        BAR();                       // tile `it` resident WG-wide
        short8 af[2], bf[4];
        #pragma unroll
        for (int mi = 0; mi < 2; ++mi)
            af[mi] = *(short8*)&sA[buf][(mh + mi * 16 + col) * 32 + l4 * 8];
        #pragma unroll
        for (int ni = 0; ni < 4; ++ni)
            bf[ni] = *(short8*)&sB[buf][(ni * 16 + col) * 32 + l4 * 8];
        #pragma unroll
        for (int mi = 0; mi < 2; ++mi)
            #pragma unroll
            for (int ni = 0; ni < 4; ++ni)
                acc[mi][ni] = __builtin_amdgcn_mfma_f32_16x16x32_bf16(af[mi], bf[ni], acc[mi][ni], 0, 0, 0);
    }

    float bcol[4];
    #pragma unroll
    for (int ni = 0; ni < 4; ++ni) bcol[ni] = bias[n0 + ni * 16 + col];

    if (mode == 2) {
        // V^T bf16: [b][hk][d][SEQ]; s contiguous over r -> b64 stores
        #pragma unroll
        for (int mi = 0; mi < 2; ++mi) {
            int m = m0 + mh + mi * 16 + l4 * 4;
            int b = m >> 11, s = m & 2047;
            #pragma unroll
            for (int ni = 0; ni < 4; ++ni) {
                int dg = n0 + ni * 16 + col;
                u16x4 pk = {f2bf(acc[mi][ni][0] + bcol[ni]), f2bf(acc[mi][ni][1] + bcol[ni]),
                            f2bf(acc[mi][ni][2] + bcol[ni]), f2bf(acc[mi][ni][3] + bcol[ni])};
                *(u16x4*)&Vtp[((size_t)(b * NKV + (dg >> 6)) * HD + (dg & 63)) * SEQ_ + s] = pk;
            }
        }
    } else {
        int nheads = (mode == 0) ? NH : NKV;
        u16* outp = (mode == 0) ? Qp : Kp;
        float osc = (mode == 0) ? 0.125f * LOG2E : 1.0f;   // fold 1/sqrt(64)*log2e into Q
        int h = n0 >> 6;
        #pragma unroll
        for (int mi = 0; mi < 2; ++mi)
            #pragma unroll
            for (int r = 0; r < 4; ++r) {
                int m = m0 + mh + mi * 16 + l4 * 4 + r;
                int b = m >> 11, s = m & 2047;
                u16* q = outp + ((size_t)(b * nheads + h) * SEQ_ + s) * HD;
                const float2* tb = rtab + (size_t)s * 32;
                #pragma unroll
                for (int p = 0; p < 2; ++p) {
                    float x0 = acc[mi][p][r] + bcol[p];
                    float x1 = acc[mi][p + 2][r] + bcol[p + 2];
                    float2 cs = tb[16 * p + col];
                    q[16 * p + col]      = f2bf((x0 * cs.x - x1 * cs.y) * osc);
                    q[16 * p + col + 32] = f2bf((x0 * cs.y + x1 * cs.x) * osc);
                }
            }
    }
}

// ---------------- Wo MFMA GEMM, 128x64 tile, XCD-affine, drain-free pipeline ----------------
__global__ __launch_bounds__(256) void gemm_wo(
    const u16* __restrict__ Abf, const u16* __restrict__ Wob, float* __restrict__ out)
{
    __shared__ __align__(16) u16 sA[2][4096];
    __shared__ __align__(16) u16 sB[2][2048];
    int tid = threadIdx.x, lane = tid & 63, wave = tid >> 6;
    int col = lane & 15, l4 = lane >> 4;
    int id = blockIdx.x;
    int xcd = id & 7, slot = id >> 3;
    int by = 4 * xcd + (slot & 3);
    int bx = slot >> 2;              // 0..15
    int m0 = by * 128, n0 = bx * 64;
    const u16* ga0 = Abf + (size_t)(m0 + (tid >> 2)) * HIDDEN + (tid & 3) * 8;
    const u16* ga1 = Abf + (size_t)(m0 + 64 + (tid >> 2)) * HIDDEN + (tid & 3) * 8;
    const u16* gb0 = Wob + (size_t)(n0 + (tid >> 2)) * HIDDEN + (tid & 3) * 8;

    f32x4 acc[2][4];
    #pragma unroll
    for (int i = 0; i < 2; ++i)
        #pragma unroll
        for (int j = 0; j < 4; ++j) acc[i][j] = (f32x4){0.f, 0.f, 0.f, 0.f};
    int mh = wave * 32;

    async_ld16(ga0, &sA[0][wave * 512]);
    async_ld16(ga1, &sA[0][2048 + wave * 512]);
    async_ld16(gb0, &sB[0][wave * 512]);
    ga0 += 32; ga1 += 32; gb0 += 32;

    for (int it = 0; it < 32; ++it) {
        int buf = it & 1;
        BAR();
        if (it + 1 < 32) {
            int nb = buf ^ 1;
            async_ld16(ga0, &sA[nb][wave * 512]);
            async_ld16(ga1, &sA[nb][2048 + wave * 512]);
            async_ld16(gb0, &sB[nb][wave * 512]);
            ga0 += 32; ga1 += 32; gb0 += 32;
            WAITVM(3);
        } else {
            WAITVM(0);
        }
        BAR();
        short8 af[2], bf[4];
        #pragma unroll
        for (int mi = 0; mi < 2; ++mi)
            af[mi] = *(short8*)&sA[buf][(mh + mi * 16 + col) * 32 + l4 * 8];
        #pragma unroll
        for (int ni = 0; ni < 4; ++ni)
            bf[ni] = *(short8*)&sB[buf][(ni * 16 + col) * 32 + l4 * 8];
        #pragma unroll
        for (int mi = 0; mi < 2; ++mi)
            #pragma unroll
            for (int ni = 0; ni < 4; ++ni)
                acc[mi][ni] = __builtin_amdgcn_mfma_f32_16x16x32_bf16(af[mi], bf[ni], acc[mi][ni], 0, 0, 0);
    }
    #pragma unroll
    for (int mi = 0; mi < 2; ++mi)
        #pragma unroll
        for (int r = 0; r < 4; ++r) {
            int m = m0 + mh + mi * 16 + l4 * 4 + r;
            #pragma unroll
            for (int ni = 0; ni < 4; ++ni)
                out[(size_t)m * HIDDEN + n0 + ni * 16 + col] = acc[mi][ni][r];
        }
}

// ---------------- MFMA flash attention v10: drain-free pipeline ----------------
// 128 q/WG, 512 thr = 8 waves (ws = wave&3: 32-q slice, kh = wave>>2: 32-key half).
// Grid (16, 32) = 512 WGs -> 2 WG/CU = 16 waves/CU. K/V dbuf; amask in LDS;
// only vmcnt ops in the loop are the 2 staging DMAs per wave. No __syncthreads in loop.
__global__ __launch_bounds__(512) void attn_mfma(
    const u16* __restrict__ Qp, const u16* __restrict__ Kp,
    const u16* __restrict__ Vtp, const float* __restrict__ ams,
    u16* __restrict__ Abf)
{
    __shared__ __align__(16) u16 smem[30720];   // K dbuf [0,8192) | V dbuf [8192,16384) | sP [16384,26624) | sAm [26624,30720)
    int tid = threadIdx.x;
    int lane = tid & 63, wave = tid >> 6;       // 0..7
    int col = lane & 31, h5 = lane >> 5;
    int sx = col & 7;
    int ws = wave & 3, kh = wave >> 2;
    int qb = blockIdx.x, bh = blockIdx.y;
    int b = bh >> 4, h = bh & 15, hk = h >> 2;
    int q0 = qb * 128;
    int qbase = q0 + ws * 32;                   // this wave's 32 queries
    int qcol = qbase + col;
    int khi = kh * 32;
    u16* sPw = smem + 16384 + wave * 1280;      // [q=col][32 keys], row stride 40 u16
    float* sAm = (float*)(smem + 26624);        // 2048 floats

    // amask -> LDS once (per-iter mask reads become lgkmcnt, not vmcnt)
    {
        int i4 = tid * 4;
        *(float4*)&sAm[i4] = *(const float4*)(ams + b * SEQ_ + i4);
    }

    // Q fragments (B-operand): lane holds Q[q=qbase+col][d = ds*16 + h5*8 + j]
    const u16* qp = Qp + ((size_t)(b * NH + h) * SEQ_ + qbase + col) * HD;
    short8 qf[4];
    #pragma unroll
    for (int ds = 0; ds < 4; ++ds)
        qf[ds] = *(const short8*)(qp + ds * 16 + h5 * 8);

    // staging: 512 threads x 16B = full 8 KB K tile + 8 KB V tile per round, XOR-swizzled
    int srow = tid >> 3;                        // 0..63
    int swc = ((tid & 7) ^ (srow & 7)) * 8;
    const u16* pK = Kp + (size_t)(b * NKV + hk) * SEQ_ * HD + (size_t)srow * HD + swc;
    const u16* pV = Vtp + (size_t)(b * NKV + hk) * HD * SEQ_ + (size_t)srow * SEQ_ + swc;

    f32x16 O[2];
    #pragma unroll
    for (int dt = 0; dt < 2; ++dt)
        #pragma unroll
        for (int e = 0; e < 16; ++e) O[dt][e] = 0.f;
    float lsum = 0.f;

    int nk = min(SEQ_, q0 + 128 + WIN);
    int nkb = (nk + 63) >> 6;

    __syncthreads();                            // sAm visible (one full drain, outside loop)

    // prologue: tile 0 -> buf 0 (2 DMAs per wave)
    async_ld16(pK, smem + wave * 512);
    async_ld16(pV, smem + 8192 + wave * 512);
    pK += 64 * HD; pV += 64;

    for (int kb = 0; kb < nkb; ++kb) {
        int buf = kb & 1;
        int k0 = kb * 64;
        BAR();                                  // readers of buf^1 (iter kb-1) done
        if (kb + 1 < nkb) {
            int nb = buf ^ 1;
            async_ld16(pK, smem + nb * 4096 + wave * 512);
            async_ld16(pV, smem + 8192 + nb * 4096 + wave * 512);
            pK += 64 * HD; pV += 64;
            WAITVM(2);                          // my tile-kb DMAs landed; kb+1's in flight
        } else {
            WAITVM(0);
        }
        BAR();                                  // tile kb resident WG-wide
        const u16* sK = smem + buf * 4096;
        const u16* sVT = smem + 8192 + buf * 4096;

        bool dead = (k0 + khi) > (qbase + 31 + WIN);   // wave-uniform
        if (!dead) {
            f32x16 St;
            #pragma unroll
            for (int e = 0; e < 16; ++e) St[e] = 0.f;
            #pragma unroll
            for (int ds = 0; ds < 4; ++ds) {
                short8 kf = *(short8*)&sK[(khi + col) * 64 + ((ds * 2 + h5) ^ sx) * 8];
                St = __builtin_amdgcn_mfma_f32_32x32x16_bf16(kf, qf[ds], St, 0, 0, 0);
            }
            bool full = (k0 + khi + 31) <= (qbase + WIN);   // wave-uniform
            float ps = 0.f;
            #pragma unroll
            for (int g = 0; g < 4; ++g) {
                int krow = 8 * g + 4 * h5;
                float4 amv = *(float4*)&sAm[k0 + khi + krow];
                float amr[4] = {amv.x, amv.y, amv.z, amv.w};
                float pe[4];
                #pragma unroll
                for (int i = 0; i < 4; ++i) {
                    float s = St[g * 4 + i] + amr[i];
                    if (!full) {
                        int kg = k0 + khi + krow + i;
                        s = (kg - qcol <= WIN) ? s : -INFINITY;
                    }
                    float e = __builtin_amdgcn_exp2f(s);   // scores pre-scaled by log2e
                    pe[i] = e;
                    ps += e;
                }
                uint2 w;
                w.x = pk_trunc(pe[0], pe[1]);
                w.y = pk_trunc(pe[2], pe[3]);
                *(uint2*)&sPw[col * 40 + g * 8 + 4 * h5] = w;   // keys 8g+4h5..+3
            }
            lsum += ps;
            // P^T B-frags: lane holds P[q=col][key = kstep*16 + h5*8 + j]
            short8 pb0 = *(short8*)&sPw[col * 40 + (0 * 2 + h5) * 8];
            short8 pb1 = *(short8*)&sPw[col * 40 + (1 * 2 + h5) * 8];
            #pragma unroll
            for (int dt = 0; dt < 2; ++dt) {
                short8 vf0 = *(short8*)&sVT[(dt * 32 + col) * 64 + ((kh * 4 + 0 + h5) ^ sx) * 8];
                O[dt] = __builtin_amdgcn_mfma_f32_32x32x16_bf16(vf0, pb0, O[dt], 0, 0, 0);
                short8 vf1 = *(short8*)&sVT[(dt * 32 + col) * 64 + ((kh * 4 + 2 + h5) ^ sx) * 8];
                O[dt] = __builtin_amdgcn_mfma_f32_32x32x16_bf16(vf1, pb1, O[dt], 0, 0, 0);
            }
        }
    }

    // ---- combine key-halves (kh=0 <- kh=1) through LDS overlay ----
    float l = lsum + __shfl_xor(lsum, 32);   // full 32-key partial for q = col
    __syncthreads();                          // loop reads done; smem reusable
    float* sO = (float*)smem;                 // [ws*32+col][68]: 64 d f32 + lsum at [64] (34816 B)
    int rq = ws * 32 + col;
    if (kh == 1) {
        #pragma unroll
        for (int dt = 0; dt < 2; ++dt)
            #pragma unroll
            for (int g = 0; g < 4; ++g) {
                float4 v = make_float4(O[dt][g * 4 + 0], O[dt][g * 4 + 1],
                                       O[dt][g * 4 + 2], O[dt][g * 4 + 3]);
                *(float4*)&sO[rq * 68 + dt * 32 + 8 * g + 4 * h5] = v;
            }
        if (h5 == 0) sO[rq * 68 + 64] = l;
    }
    __syncthreads();
    if (kh == 0) {
        float linv = 1.0f / (l + sO[rq * 68 + 64]);
        u16* op = Abf + (size_t)(b * SEQ_ + qbase + col) * HIDDEN + h * HD;
        #pragma unroll
        for (int dt = 0; dt < 2; ++dt)
            #pragma unroll
            for (int g = 0; g < 4; ++g) {
                float4 v = *(float4*)&sO[rq * 68 + dt * 32 + 8 * g + 4 * h5];
                u16x4 pk = {f2bf((O[dt][g * 4 + 0] + v.x) * linv),
                            f2bf((O[dt][g * 4 + 1] + v.y) * linv),
                            f2bf((O[dt][g * 4 + 2] + v.z) * linv),
                            f2bf((O[dt][g * 4 + 3] + v.w) * linv)};
                *(u16x4*)(op + dt * 32 + 8 * g + 4 * h5) = pk;
            }
    }
}

extern "C" void kernel_launch(void* const* d_in, const int* in_sizes, int n_in,
                              void* d_out, int out_size, void* d_ws, size_t ws_size,
                              hipStream_t stream) {
    const float* X  = (const float*)d_in[0];
    const float* am = (const float*)d_in[1];
    const float* Wq = (const float*)d_in[2];
    const float* bq = (const float*)d_in[3];
    const float* Wk = (const float*)d_in[4];
    const float* bk = (const float*)d_in[5];
    const float* Wv = (const float*)d_in[6];
    const float* bv = (const float*)d_in[7];
    const float* Wo = (const float*)d_in[8];
    float* out = (float*)d_out;

    const int M = BS_ * SEQ_;            // 4096
    u16* Qp  = (u16*)d_ws;                         // 8 MB
    u16* Kp  = Qp + (size_t)M * HIDDEN;            // 2 MB
    u16* Vtp = Kp + (size_t)M * 256;               // 2 MB
    u16* Xb  = Vtp + (size_t)M * 256;              // 8 MB
    u16* Wqb = Xb + (size_t)M * HIDDEN;            // 2 MB
    u16* Wkb = Wqb + (size_t)HIDDEN * HIDDEN;      // 0.5 MB
    u16* Wvb = Wkb + (size_t)256 * HIDDEN;         // 0.5 MB
    u16* Wob = Wvb + (size_t)256 * HIDDEN;         // 2 MB
    float* ams = (float*)(Wob + (size_t)HIDDEN * HIDDEN);  // 16 KB
    float2* rtab = (float2*)(ams + BS_ * SEQ_);            // 512 KB RoPE LUT
    u16* Abf = Xb;  // alias: Xb consumed by gemm_qkv before attn writes Abf

    dim3 blk(256);
    cast6<<<dim3(6916), blk, 0, stream>>>(X, Wq, Wk, Wv, Wo, am, Xb, Wqb, Wkb, Wvb, Wob, ams, rtab);
    gemm_qkv<<<dim3(768), blk, 0, stream>>>(Xb, Wqb, Wkb, Wvb, bq, bk, bv, rtab, Qp, Kp, Vtp);
    attn_mfma<<<dim3(SEQ_ / 128, BS_ * NH), dim3(512), 0, stream>>>(Qp, Kp, Vtp, ams, Abf);
    gemm_wo<<<dim3(512), blk, 0, stream>>>(Abf, Wob, out);
}